// Round 1
// baseline (1130.533 us; speedup 1.0000x reference)
//
#include <hip/hip_runtime.h>

#define N_NODES 10000
#define N_EDGES 320000
#define FEAT    256
#define NB      16   // nodes per block in linear kernel

// ---------------------------------------------------------------------------
// Stage 1: scatter-sum. One wave (64 lanes) per edge; each lane handles 4
// consecutive floats (float4 = 16B/lane, fully coalesced 1KB row read).
// fp32 atomicAdd into agg[dst]; lane 0 counts the edge.
// ---------------------------------------------------------------------------
__global__ __launch_bounds__(256) void scatter_kernel(
    const float* __restrict__ src,
    const int*   __restrict__ dst_idx,
    float*       __restrict__ agg,
    int*         __restrict__ cnt)
{
    const int gtid = blockIdx.x * blockDim.x + threadIdx.x;
    const int e    = gtid >> 6;          // one wave64 per edge
    const int lane = threadIdx.x & 63;
    if (e >= N_EDGES) return;

    const int d = dst_idx[e];            // wave-uniform (broadcast load)

    const float4 v = *reinterpret_cast<const float4*>(src + (size_t)e * FEAT + lane * 4);
    float* p = agg + (size_t)d * FEAT + lane * 4;
    atomicAdd(p + 0, v.x);
    atomicAdd(p + 1, v.y);
    atomicAdd(p + 2, v.z);
    atomicAdd(p + 3, v.w);

    if (lane == 0) atomicAdd(cnt + d, 1);
}

// ---------------------------------------------------------------------------
// Stage 2: mean + linear.  out[n][j] = inv(cnt[n]) * sum_f agg[n][f]*W[j][f] + b[j]
// Block = 256 threads (thread t owns output feature j = t), NB=16 nodes/block.
// agg rows staged in LDS; LDS reads are same-address broadcasts (free).
// W rows streamed per-thread (L2-resident, 256KB total).
// ---------------------------------------------------------------------------
__global__ __launch_bounds__(256) void linear_kernel(
    const float* __restrict__ agg,
    const int*   __restrict__ cnt,
    const float* __restrict__ W,
    const float* __restrict__ bias,
    float*       __restrict__ out)
{
    __shared__ float s_rows[NB][FEAT];
    __shared__ float s_inv[NB];

    const int t  = threadIdx.x;          // output feature j
    const int n0 = blockIdx.x * NB;

    #pragma unroll
    for (int n = 0; n < NB; ++n) {
        s_rows[n][t] = agg[(size_t)(n0 + n) * FEAT + t];   // coalesced
    }
    if (t < NB) {
        const int c = cnt[n0 + t];
        s_inv[t] = (c > 0) ? 1.0f / (float)c : 0.0f;
    }
    __syncthreads();

    float acc[NB];
    #pragma unroll
    for (int n = 0; n < NB; ++n) acc[n] = 0.0f;

    const float* wrow = W + (size_t)t * FEAT;   // W[j][f], contiguous in f
    for (int f = 0; f < FEAT; f += 4) {
        const float4 w4 = *reinterpret_cast<const float4*>(wrow + f);
        #pragma unroll
        for (int n = 0; n < NB; ++n) {
            const float4 s4 = *reinterpret_cast<const float4*>(&s_rows[n][f]);
            acc[n] = fmaf(s4.x, w4.x, acc[n]);
            acc[n] = fmaf(s4.y, w4.y, acc[n]);
            acc[n] = fmaf(s4.z, w4.z, acc[n]);
            acc[n] = fmaf(s4.w, w4.w, acc[n]);
        }
    }

    const float bj = bias[t];
    #pragma unroll
    for (int n = 0; n < NB; ++n) {
        out[(size_t)(n0 + n) * FEAT + t] = acc[n] * s_inv[n] + bj;
    }
}

// ---------------------------------------------------------------------------
extern "C" void kernel_launch(void* const* d_in, const int* in_sizes, int n_in,
                              void* d_out, int out_size, void* d_ws, size_t ws_size,
                              hipStream_t stream)
{
    const float* src = (const float*)d_in[0];
    const int*   ei  = (const int*)d_in[1];          // [2, E] int32
    const int*   dst = ei + N_EDGES;                 // row 1 = destination nodes
    const float* W   = (const float*)d_in[3];
    const float* b   = (const float*)d_in[4];
    float*       out = (float*)d_out;

    const size_t agg_bytes = (size_t)N_NODES * FEAT * sizeof(float);  // 10.24 MB
    float* agg = (float*)d_ws;
    int*   cnt = (int*)((char*)d_ws + agg_bytes);

    // zero agg + counts each call (ws is not re-poisoned between replays)
    hipMemsetAsync(d_ws, 0, agg_bytes + (size_t)N_NODES * sizeof(int), stream);

    // one wave per edge -> 4 edges per 256-thread block
    scatter_kernel<<<N_EDGES / 4, 256, 0, stream>>>(src, dst, agg, cnt);

    // 16 nodes per block
    linear_kernel<<<N_NODES / NB, 256, 0, stream>>>(agg, cnt, W, b, out);
}

// Round 2
// 211.026 us; speedup vs baseline: 5.3573x; 5.3573x over previous
//
#include <hip/hip_runtime.h>

#define N_NODES 10000
#define N_EDGES 320000
#define FEAT    256
#define NB      32    // nodes per block in linear kernel
#define SCAN_T  256
#define CHUNK   40    // SCAN_T*CHUNK = 10240 >= N_NODES

// ---------------------------------------------------------------------------
// Stage 1: histogram of destination nodes (int atomics on 40KB — cheap).
// ---------------------------------------------------------------------------
__global__ __launch_bounds__(256) void hist_kernel(
    const int* __restrict__ dst, int* __restrict__ cnt)
{
    const int e = blockIdx.x * 256 + threadIdx.x;
    if (e < N_EDGES) atomicAdd(&cnt[dst[e]], 1);
}

// ---------------------------------------------------------------------------
// Stage 2: single-block exclusive scan of cnt -> offs[10001], curs[10000].
// 256 threads x 40 elements each.
// ---------------------------------------------------------------------------
__global__ __launch_bounds__(SCAN_T) void scan_kernel(
    const int* __restrict__ cnt, int* __restrict__ offs, int* __restrict__ curs)
{
    __shared__ int sums[SCAN_T];
    const int t = threadIdx.x;
    const int base = t * CHUNK;

    int s = 0;
    for (int i = 0; i < CHUNK; ++i) {
        const int idx = base + i;
        if (idx < N_NODES) s += cnt[idx];
    }
    sums[t] = s;
    __syncthreads();

    // Hillis-Steele inclusive scan over 256 partials
    for (int off = 1; off < SCAN_T; off <<= 1) {
        const int v = (t >= off) ? sums[t - off] : 0;
        __syncthreads();
        sums[t] += v;
        __syncthreads();
    }

    int run = sums[t] - s;   // exclusive prefix for this thread's chunk
    for (int i = 0; i < CHUNK; ++i) {
        const int idx = base + i;
        if (idx < N_NODES) {
            offs[idx] = run;
            curs[idx] = run;
            run += cnt[idx];
        }
    }
    if (t == SCAN_T - 1) offs[N_NODES] = run;   // = N_EDGES
}

// ---------------------------------------------------------------------------
// Stage 3: bucket fill — edge ids grouped by destination node.
// ---------------------------------------------------------------------------
__global__ __launch_bounds__(256) void fill_kernel(
    const int* __restrict__ dst, int* __restrict__ curs, int* __restrict__ bucket)
{
    const int e = blockIdx.x * 256 + threadIdx.x;
    if (e < N_EDGES) {
        const int pos = atomicAdd(&curs[dst[e]], 1);
        bucket[pos] = e;
    }
}

// ---------------------------------------------------------------------------
// Stage 4: gather + mean. One wave (64 lanes) per node; lane t owns features
// [4t, 4t+4) as float4. Edge list staged in LDS 64 at a time; each edge read
// is a fully-coalesced 1KB contiguous row. Zero atomics. Writes MEAN to out.
// ---------------------------------------------------------------------------
__global__ __launch_bounds__(64) void gather_kernel(
    const float* __restrict__ src,
    const int*   __restrict__ offs,
    const int*   __restrict__ bucket,
    float*       __restrict__ out_mean)
{
    __shared__ int s_e[64];
    const int n = blockIdx.x;
    const int t = threadIdx.x;        // 0..63
    const int start = offs[n], end = offs[n + 1];

    float4 acc = make_float4(0.f, 0.f, 0.f, 0.f);
    for (int base = start; base < end; base += 64) {
        const int m = min(64, end - base);
        if (t < m) s_e[t] = bucket[base + t];
        __syncthreads();
        for (int i = 0; i < m; ++i) {
            const float4 v = *reinterpret_cast<const float4*>(
                src + (size_t)s_e[i] * FEAT + t * 4);
            acc.x += v.x; acc.y += v.y; acc.z += v.z; acc.w += v.w;
        }
        __syncthreads();
    }

    const int deg = end - start;
    const float inv = (deg > 0) ? 1.0f / (float)deg : 0.0f;
    float4 r = make_float4(acc.x * inv, acc.y * inv, acc.z * inv, acc.w * inv);
    *reinterpret_cast<float4*>(out_mean + (size_t)n * FEAT + t * 4) = r;
}

// ---------------------------------------------------------------------------
// Stage 5: in-place linear. y[n][j] = sum_f x[n][f]*W[j][f] + b[j].
// Block reads its NB rows into LDS first, so x==y aliasing is safe.
// LDS reads are same-address broadcasts (free). W rows stream from L2.
// ---------------------------------------------------------------------------
__global__ __launch_bounds__(256) void linear_kernel(
    const float* x,                      // may alias y (in-place)
    const float* __restrict__ W,
    const float* __restrict__ bias,
    float*       y)
{
    __shared__ float s_rows[NB][FEAT];
    const int t  = threadIdx.x;          // output feature j
    const int n0 = blockIdx.x * NB;

    #pragma unroll
    for (int n = 0; n < NB; ++n) {
        const int node = n0 + n;
        s_rows[n][t] = (node < N_NODES) ? x[(size_t)node * FEAT + t] : 0.f;
    }
    __syncthreads();

    float acc[NB];
    #pragma unroll
    for (int n = 0; n < NB; ++n) acc[n] = 0.0f;

    const float* wrow = W + (size_t)t * FEAT;   // W[j][f], contiguous in f
    for (int f = 0; f < FEAT; f += 4) {
        const float4 w4 = *reinterpret_cast<const float4*>(wrow + f);
        #pragma unroll
        for (int n = 0; n < NB; ++n) {
            const float4 s4 = *reinterpret_cast<const float4*>(&s_rows[n][f]);
            acc[n] = fmaf(s4.x, w4.x, acc[n]);
            acc[n] = fmaf(s4.y, w4.y, acc[n]);
            acc[n] = fmaf(s4.z, w4.z, acc[n]);
            acc[n] = fmaf(s4.w, w4.w, acc[n]);
        }
    }

    const float bj = bias[t];
    #pragma unroll
    for (int n = 0; n < NB; ++n) {
        const int node = n0 + n;
        if (node < N_NODES) y[(size_t)node * FEAT + t] = acc[n] + bj;
    }
}

// ---------------------------------------------------------------------------
extern "C" void kernel_launch(void* const* d_in, const int* in_sizes, int n_in,
                              void* d_out, int out_size, void* d_ws, size_t ws_size,
                              hipStream_t stream)
{
    const float* src = (const float*)d_in[0];
    const int*   ei  = (const int*)d_in[1];          // [2, E] int32
    const int*   dst = ei + N_EDGES;                 // row 1 = destination nodes
    const float* W   = (const float*)d_in[3];
    const float* b   = (const float*)d_in[4];
    float*       out = (float*)d_out;

    // workspace layout (ints), generously padded: ~1.4 MB total
    int* cnt    = (int*)d_ws;            // [10000]
    int* offs   = cnt  + 10240;          // [10001]
    int* curs   = offs + 10240;          // [10000]
    int* bucket = curs + 10240;          // [320000]

    hipMemsetAsync(cnt, 0, N_NODES * sizeof(int), stream);

    hist_kernel<<<(N_EDGES + 255) / 256, 256, 0, stream>>>(dst, cnt);
    scan_kernel<<<1, SCAN_T, 0, stream>>>(cnt, offs, curs);
    fill_kernel<<<(N_EDGES + 255) / 256, 256, 0, stream>>>(dst, curs, bucket);

    // gather writes the per-node MEAN into d_out (scratch use), then the
    // linear kernel transforms it in place.
    gather_kernel<<<N_NODES, 64, 0, stream>>>(src, offs, bucket, out);
    linear_kernel<<<(N_NODES + NB - 1) / NB, 256, 0, stream>>>(out, W, b, out);
}

// Round 3
// 202.620 us; speedup vs baseline: 5.5796x; 1.0415x over previous
//
#include <hip/hip_runtime.h>

#define N_NODES 10000
#define N_EDGES 320000
#define FEAT    256
#define NB      32    // nodes per block in linear kernel
#define SCAN_T  512
#define CHUNK   20    // SCAN_T*CHUNK = 10240 >= N_NODES
#define GT      256   // gather block threads (4 waves)

// ---------------------------------------------------------------------------
// Stage 1: histogram of destination nodes (int atomics on 40KB — cheap).
// ---------------------------------------------------------------------------
__global__ __launch_bounds__(256) void hist_kernel(
    const int* __restrict__ dst, int* __restrict__ cnt)
{
    const int e = blockIdx.x * 256 + threadIdx.x;
    if (e < N_EDGES) atomicAdd(&cnt[dst[e]], 1);
}

// ---------------------------------------------------------------------------
// Stage 2: single-block exclusive scan of cnt -> offs[10001], curs[10000].
// ---------------------------------------------------------------------------
__global__ __launch_bounds__(SCAN_T) void scan_kernel(
    const int* __restrict__ cnt, int* __restrict__ offs, int* __restrict__ curs)
{
    __shared__ int sums[SCAN_T];
    const int t = threadIdx.x;
    const int base = t * CHUNK;

    int s = 0;
    #pragma unroll
    for (int i = 0; i < CHUNK; ++i) {
        const int idx = base + i;
        if (idx < N_NODES) s += cnt[idx];
    }
    sums[t] = s;
    __syncthreads();

    // Hillis-Steele inclusive scan over SCAN_T partials
    for (int off = 1; off < SCAN_T; off <<= 1) {
        const int v = (t >= off) ? sums[t - off] : 0;
        __syncthreads();
        sums[t] += v;
        __syncthreads();
    }

    int run = sums[t] - s;   // exclusive prefix for this thread's chunk
    #pragma unroll
    for (int i = 0; i < CHUNK; ++i) {
        const int idx = base + i;
        if (idx < N_NODES) {
            offs[idx] = run;
            curs[idx] = run;
            run += cnt[idx];
        }
    }
    if (t == SCAN_T - 1) offs[N_NODES] = run;   // = N_EDGES
}

// ---------------------------------------------------------------------------
// Stage 3: bucket fill — edge ids grouped by destination node.
// ---------------------------------------------------------------------------
__global__ __launch_bounds__(256) void fill_kernel(
    const int* __restrict__ dst, int* __restrict__ curs, int* __restrict__ bucket)
{
    const int e = blockIdx.x * 256 + threadIdx.x;
    if (e < N_EDGES) {
        const int pos = atomicAdd(&curs[dst[e]], 1);
        bucket[pos] = e;
    }
}

// ---------------------------------------------------------------------------
// Stage 4: gather + mean. One 256-thread block (4 waves) per node.
// Wave w handles edges base+w, base+w+4, ...; lane t&63 owns features
// [4*lane, 4*lane+4) as float4 (fully coalesced 1KB row per load).
// Cross-wave reduce via 3KB LDS. Zero atomics. Writes MEAN to out.
// ---------------------------------------------------------------------------
__global__ __launch_bounds__(GT) void gather_kernel(
    const float* __restrict__ src,
    const int*   __restrict__ offs,
    const int*   __restrict__ bucket,
    float*       __restrict__ out_mean)
{
    __shared__ int   s_e[GT];
    __shared__ float s_red[3][FEAT];

    const int n    = blockIdx.x;
    const int t    = threadIdx.x;
    const int lane = t & 63;
    const int w    = t >> 6;
    const int start = offs[n], end = offs[n + 1];

    float4 acc = make_float4(0.f, 0.f, 0.f, 0.f);
    for (int base = start; base < end; base += GT) {
        const int m = min(GT, end - base);
        if (t < m) s_e[t] = bucket[base + t];
        __syncthreads();
        for (int i = w; i < m; i += 4) {
            const float4 v = *reinterpret_cast<const float4*>(
                src + (size_t)s_e[i] * FEAT + lane * 4);
            acc.x += v.x; acc.y += v.y; acc.z += v.z; acc.w += v.w;
        }
        __syncthreads();
    }

    // cross-wave reduce: waves 1..3 dump partials, wave 0 accumulates
    if (w > 0) *reinterpret_cast<float4*>(&s_red[w - 1][lane * 4]) = acc;
    __syncthreads();
    if (w == 0) {
        #pragma unroll
        for (int k = 0; k < 3; ++k) {
            const float4 r = *reinterpret_cast<const float4*>(&s_red[k][lane * 4]);
            acc.x += r.x; acc.y += r.y; acc.z += r.z; acc.w += r.w;
        }
        const int deg = end - start;
        const float inv = (deg > 0) ? 1.0f / (float)deg : 0.0f;
        const float4 r = make_float4(acc.x * inv, acc.y * inv, acc.z * inv, acc.w * inv);
        *reinterpret_cast<float4*>(out_mean + (size_t)n * FEAT + lane * 4) = r;
    }
}

// ---------------------------------------------------------------------------
// Stage 5: in-place linear. y[n][j] = sum_f x[n][f]*W[j][f] + b[j].
// Block reads its NB rows into LDS first, so x==y aliasing is safe.
// LDS reads are same-address broadcasts (free). W rows stream from L2,
// with immediate L1 reuse (each 64B line feeds 4 consecutive f-iters).
// ---------------------------------------------------------------------------
__global__ __launch_bounds__(256) void linear_kernel(
    const float* x,                      // may alias y (in-place)
    const float* __restrict__ W,
    const float* __restrict__ bias,
    float*       y)
{
    __shared__ float s_rows[NB][FEAT];
    const int t  = threadIdx.x;          // output feature j
    const int n0 = blockIdx.x * NB;

    #pragma unroll
    for (int n = 0; n < NB; ++n) {
        const int node = n0 + n;
        s_rows[n][t] = (node < N_NODES) ? x[(size_t)node * FEAT + t] : 0.f;
    }
    __syncthreads();

    float acc[NB];
    #pragma unroll
    for (int n = 0; n < NB; ++n) acc[n] = 0.0f;

    const float* wrow = W + (size_t)t * FEAT;   // W[j][f], contiguous in f
    for (int f = 0; f < FEAT; f += 4) {
        const float4 w4 = *reinterpret_cast<const float4*>(wrow + f);
        #pragma unroll
        for (int n = 0; n < NB; ++n) {
            const float4 s4 = *reinterpret_cast<const float4*>(&s_rows[n][f]);
            acc[n] = fmaf(s4.x, w4.x, acc[n]);
            acc[n] = fmaf(s4.y, w4.y, acc[n]);
            acc[n] = fmaf(s4.z, w4.z, acc[n]);
            acc[n] = fmaf(s4.w, w4.w, acc[n]);
        }
    }

    const float bj = bias[t];
    #pragma unroll
    for (int n = 0; n < NB; ++n) {
        const int node = n0 + n;
        if (node < N_NODES) y[(size_t)node * FEAT + t] = acc[n] + bj;
    }
}

// ---------------------------------------------------------------------------
extern "C" void kernel_launch(void* const* d_in, const int* in_sizes, int n_in,
                              void* d_out, int out_size, void* d_ws, size_t ws_size,
                              hipStream_t stream)
{
    const float* src = (const float*)d_in[0];
    const int*   ei  = (const int*)d_in[1];          // [2, E] int32
    const int*   dst = ei + N_EDGES;                 // row 1 = destination nodes
    const float* W   = (const float*)d_in[3];
    const float* b   = (const float*)d_in[4];
    float*       out = (float*)d_out;

    // workspace layout (ints), generously padded: ~1.4 MB total
    int* cnt    = (int*)d_ws;            // [10000]
    int* offs   = cnt  + 10240;          // [10001]
    int* curs   = offs + 10240;          // [10000]
    int* bucket = curs + 10240;          // [320000]

    hipMemsetAsync(cnt, 0, N_NODES * sizeof(int), stream);

    hist_kernel<<<(N_EDGES + 255) / 256, 256, 0, stream>>>(dst, cnt);
    scan_kernel<<<1, SCAN_T, 0, stream>>>(cnt, offs, curs);
    fill_kernel<<<(N_EDGES + 255) / 256, 256, 0, stream>>>(dst, curs, bucket);

    // gather writes the per-node MEAN into d_out (scratch use), then the
    // linear kernel transforms it in place.
    gather_kernel<<<N_NODES, GT, 0, stream>>>(src, offs, bucket, out);
    linear_kernel<<<(N_NODES + NB - 1) / NB, 256, 0, stream>>>(out, W, b, out);
}

// Round 4
// 178.364 us; speedup vs baseline: 6.3383x; 1.1360x over previous
//
#include <hip/hip_runtime.h>

#define N_NODES 10000
#define N_EDGES 320000
#define FEAT    256
#define NB      16    // nodes per block in linear kernel
#define SCAN_T  512
#define CHUNK   20    // SCAN_T*CHUNK = 10240 >= N_NODES
#define GT      256   // gather block threads (4 waves)

// ---------------------------------------------------------------------------
// Stage 1: histogram of destination nodes (int atomics on 40KB — cheap).
// ---------------------------------------------------------------------------
__global__ __launch_bounds__(256) void hist_kernel(
    const int* __restrict__ dst, int* __restrict__ cnt)
{
    const int e = blockIdx.x * 256 + threadIdx.x;
    if (e < N_EDGES) atomicAdd(&cnt[dst[e]], 1);
}

// ---------------------------------------------------------------------------
// Stage 2: single-block exclusive scan of cnt -> offs[10001], curs[10000].
// ---------------------------------------------------------------------------
__global__ __launch_bounds__(SCAN_T) void scan_kernel(
    const int* __restrict__ cnt, int* __restrict__ offs, int* __restrict__ curs)
{
    __shared__ int sums[SCAN_T];
    const int t = threadIdx.x;
    const int base = t * CHUNK;

    int s = 0;
    #pragma unroll
    for (int i = 0; i < CHUNK; ++i) {
        const int idx = base + i;
        if (idx < N_NODES) s += cnt[idx];
    }
    sums[t] = s;
    __syncthreads();

    for (int off = 1; off < SCAN_T; off <<= 1) {
        const int v = (t >= off) ? sums[t - off] : 0;
        __syncthreads();
        sums[t] += v;
        __syncthreads();
    }

    int run = sums[t] - s;   // exclusive prefix for this thread's chunk
    #pragma unroll
    for (int i = 0; i < CHUNK; ++i) {
        const int idx = base + i;
        if (idx < N_NODES) {
            offs[idx] = run;
            curs[idx] = run;
            run += cnt[idx];
        }
    }
    if (t == SCAN_T - 1) offs[N_NODES] = run;   // = N_EDGES
}

// ---------------------------------------------------------------------------
// Stage 3: bucket fill — edge ids grouped by destination node.
// ---------------------------------------------------------------------------
__global__ __launch_bounds__(256) void fill_kernel(
    const int* __restrict__ dst, int* __restrict__ curs, int* __restrict__ bucket)
{
    const int e = blockIdx.x * 256 + threadIdx.x;
    if (e < N_EDGES) {
        const int pos = atomicAdd(&curs[dst[e]], 1);
        bucket[pos] = e;
    }
}

// ---------------------------------------------------------------------------
// Stage 4: gather + mean. One 256-thread block (4 waves) per node.
// Wave w owns bucket positions start+w, +4, +8, ... (stride 4). No LDS in
// the hot loop: edge ids are read directly from the L2-resident bucket
// (all-lanes-same-address -> broadcast). Manual unroll x4 with 4 independent
// accumulators keeps 4 index loads + 4 coalesced 1KB row loads in flight.
// ---------------------------------------------------------------------------
__global__ __launch_bounds__(GT) void gather_kernel(
    const float* __restrict__ src,
    const int*   __restrict__ offs,
    const int*   __restrict__ bucket,
    float*       __restrict__ out_mean)
{
    __shared__ float s_red[3][FEAT];

    const int n    = blockIdx.x;
    const int t    = threadIdx.x;
    const int lane = t & 63;
    const int w    = t >> 6;
    const int start = offs[n], end = offs[n + 1];
    const size_t foff = (size_t)(lane * 4);

    float4 a0 = make_float4(0.f,0.f,0.f,0.f);
    float4 a1 = a0, a2 = a0, a3 = a0;

    const int base_w = start + w;
    const int K = (end > base_w) ? (end - base_w + 3) >> 2 : 0;  // this wave's edge count

    int k = 0;
    for (; k + 4 <= K; k += 4) {
        const int p  = base_w + 4 * k;
        const int e0 = bucket[p];
        const int e1 = bucket[p + 4];
        const int e2 = bucket[p + 8];
        const int e3 = bucket[p + 12];
        const float4 v0 = *reinterpret_cast<const float4*>(src + (size_t)e0 * FEAT + foff);
        const float4 v1 = *reinterpret_cast<const float4*>(src + (size_t)e1 * FEAT + foff);
        const float4 v2 = *reinterpret_cast<const float4*>(src + (size_t)e2 * FEAT + foff);
        const float4 v3 = *reinterpret_cast<const float4*>(src + (size_t)e3 * FEAT + foff);
        a0.x += v0.x; a0.y += v0.y; a0.z += v0.z; a0.w += v0.w;
        a1.x += v1.x; a1.y += v1.y; a1.z += v1.z; a1.w += v1.w;
        a2.x += v2.x; a2.y += v2.y; a2.z += v2.z; a2.w += v2.w;
        a3.x += v3.x; a3.y += v3.y; a3.z += v3.z; a3.w += v3.w;
    }
    for (; k < K; ++k) {
        const int e0 = bucket[base_w + 4 * k];
        const float4 v0 = *reinterpret_cast<const float4*>(src + (size_t)e0 * FEAT + foff);
        a0.x += v0.x; a0.y += v0.y; a0.z += v0.z; a0.w += v0.w;
    }

    float4 acc = make_float4(a0.x + a1.x + a2.x + a3.x,
                             a0.y + a1.y + a2.y + a3.y,
                             a0.z + a1.z + a2.z + a3.z,
                             a0.w + a1.w + a2.w + a3.w);

    // cross-wave reduce: waves 1..3 dump partials, wave 0 accumulates
    if (w > 0) *reinterpret_cast<float4*>(&s_red[w - 1][lane * 4]) = acc;
    __syncthreads();
    if (w == 0) {
        #pragma unroll
        for (int q = 0; q < 3; ++q) {
            const float4 r = *reinterpret_cast<const float4*>(&s_red[q][lane * 4]);
            acc.x += r.x; acc.y += r.y; acc.z += r.z; acc.w += r.w;
        }
        const int deg = end - start;
        const float inv = (deg > 0) ? 1.0f / (float)deg : 0.0f;
        const float4 r = make_float4(acc.x * inv, acc.y * inv, acc.z * inv, acc.w * inv);
        *reinterpret_cast<float4*>(out_mean + (size_t)n * FEAT + lane * 4) = r;
    }
}

// ---------------------------------------------------------------------------
// Stage 5: in-place linear. y[n][j] = sum_f x[n][f]*W[j][f] + b[j].
// NB=16 -> 625 blocks (~2.4/CU). Rows staged in LDS (x may alias y).
// ---------------------------------------------------------------------------
__global__ __launch_bounds__(256) void linear_kernel(
    const float* x,                      // may alias y (in-place)
    const float* __restrict__ W,
    const float* __restrict__ bias,
    float*       y)
{
    __shared__ float s_rows[NB][FEAT];
    const int t  = threadIdx.x;          // output feature j
    const int n0 = blockIdx.x * NB;

    #pragma unroll
    for (int n = 0; n < NB; ++n) {
        const int node = n0 + n;
        s_rows[n][t] = (node < N_NODES) ? x[(size_t)node * FEAT + t] : 0.f;
    }
    __syncthreads();

    float acc[NB];
    #pragma unroll
    for (int n = 0; n < NB; ++n) acc[n] = 0.0f;

    const float* wrow = W + (size_t)t * FEAT;   // W[j][f], contiguous in f
    for (int f = 0; f < FEAT; f += 4) {
        const float4 w4 = *reinterpret_cast<const float4*>(wrow + f);
        #pragma unroll
        for (int n = 0; n < NB; ++n) {
            const float4 s4 = *reinterpret_cast<const float4*>(&s_rows[n][f]);
            acc[n] = fmaf(s4.x, w4.x, acc[n]);
            acc[n] = fmaf(s4.y, w4.y, acc[n]);
            acc[n] = fmaf(s4.z, w4.z, acc[n]);
            acc[n] = fmaf(s4.w, w4.w, acc[n]);
        }
    }

    const float bj = bias[t];
    #pragma unroll
    for (int n = 0; n < NB; ++n) {
        const int node = n0 + n;
        if (node < N_NODES) y[(size_t)node * FEAT + t] = acc[n] + bj;
    }
}

// ---------------------------------------------------------------------------
extern "C" void kernel_launch(void* const* d_in, const int* in_sizes, int n_in,
                              void* d_out, int out_size, void* d_ws, size_t ws_size,
                              hipStream_t stream)
{
    const float* src = (const float*)d_in[0];
    const int*   ei  = (const int*)d_in[1];          // [2, E] int32
    const int*   dst = ei + N_EDGES;                 // row 1 = destination nodes
    const float* W   = (const float*)d_in[3];
    const float* b   = (const float*)d_in[4];
    float*       out = (float*)d_out;

    // workspace layout (ints), generously padded: ~1.4 MB total
    int* cnt    = (int*)d_ws;            // [10000]
    int* offs   = cnt  + 10240;          // [10001]
    int* curs   = offs + 10240;          // [10000]
    int* bucket = curs + 10240;          // [320000]

    hipMemsetAsync(cnt, 0, N_NODES * sizeof(int), stream);

    hist_kernel<<<(N_EDGES + 255) / 256, 256, 0, stream>>>(dst, cnt);
    scan_kernel<<<1, SCAN_T, 0, stream>>>(cnt, offs, curs);
    fill_kernel<<<(N_EDGES + 255) / 256, 256, 0, stream>>>(dst, curs, bucket);

    gather_kernel<<<N_NODES, GT, 0, stream>>>(src, offs, bucket, out);
    linear_kernel<<<(N_NODES + NB - 1) / NB, 256, 0, stream>>>(out, W, b, out);
}